// Round 9
// baseline (644.747 us; speedup 1.0000x reference)
//
#include <hip/hip_runtime.h>

typedef unsigned short u16;
typedef unsigned int   u32;
typedef __attribute__((ext_vector_type(4))) float f32x4;
typedef __attribute__((ext_vector_type(8))) short s16x8;

#define TT 12
#define NN 10000
#define EE 160000
#define DD 128
#define OO 64

__device__ __forceinline__ u16 f2bf(float f) {
  union { float f; u32 u; } x; x.f = f;
  u32 r = x.u + 0x7FFFu + ((x.u >> 16) & 1u);   // RNE
  return (u16)(r >> 16);
}
__device__ __forceinline__ float bf2f(u16 v) {
  union { u32 u; float f; } x; x.u = (u32)v << 16; return x.f;
}

// async global->LDS, 16B per lane; LDS dest = wave-uniform base + lane*16
__device__ __forceinline__ void gload_lds16(const u16* g, u16* l) {
  __builtin_amdgcn_global_load_lds(
      (const __attribute__((address_space(1))) u32*)(const void*)g,
      (__attribute__((address_space(3))) u32*)(void*)l, 16, 0, 0);
}

// ---------------- fused prep: pack (coalesced reads, pre-swizzled Wp) + cvt + count ----------------
__global__ __launch_bounds__(256) void prep_kernel(
    const float* __restrict__ x, const float* __restrict__ hs,
    const int* __restrict__ dst,
    const float* __restrict__ Wself, const float* __restrict__ Wneigh,
    const float* __restrict__ b, const float* __restrict__ Wout,
    u16* __restrict__ xb, float* __restrict__ h0f, u16* __restrict__ hb0,
    float* __restrict__ h1f, u16* __restrict__ hb1,
    int* __restrict__ deg, u16* __restrict__ Wp,
    float* __restrict__ biasbuf, u16* __restrict__ WoT,
    int nx8, int nh8half, int E) {
  int gid = blockIdx.x * 256 + threadIdx.x;
  const int NWP = 2 * 256 * 512;
  const int NPACK = NWP + 64 * 128 + 512;
  int cvtXEnd = NPACK + nx8;
  int cvtHEnd = cvtXEnd + 2 * nh8half;
  int cntEnd  = cvtHEnd + E;
  if (gid < NPACK) {
    int pg = gid;
    if (pg < NWP) {
      // source-linear walk: s = ((j*8+gm)*128 + kd)*128 + cc  -> coalesced reads
      int cc = pg & 127;
      int kd = (pg >> 7) & 127;
      int gm = (pg >> 14) & 7;          // 0-3: Wself g2..5, 4-7: Wneigh g2..5
      int j  = pg >> 17;
      int gate = 2 + (gm & 3);
      int neigh = gm >> 2;
      const float* M = neigh ? Wneigh : Wself;
      float v = M[(((j * 6) + gate) * 128 + kd) * 128 + cc];
      int c = cc + ((gate >= 4) ? 128 : 0);
      int seg = (gate & 1) * 2 + neigh;
      int k = seg * 128 + kd;
      int kc = k >> 6, k6 = k & 63;
      int ksw = ((k6 & ~7) ^ ((c & 7) << 3)) | (k6 & 7);   // pre-swizzle for linear LDS stage
      Wp[(size_t)j * 131072 + c * 512 + kc * 64 + ksw] = f2bf(v);
    } else if (pg < NWP + 64 * 128) {
      int i = pg - NWP;
      int c = i >> 7, k = i & 127;               // WoT[c][k] = Wout[k][c]
      WoT[i] = f2bf(Wout[k * OO + c]);
    } else {
      int i = pg - NWP - 64 * 128;
      int j = i >> 8, g = (i >> 7) & 1, d = i & 127;
      int g1 = g ? 4 : 2, g2 = g ? 5 : 3;
      biasbuf[i] = b[(j * 6 + g1) * 128 + d] + b[(j * 6 + g2) * 128 + d];
    }
  } else if (gid < cvtXEnd) {
    int i8 = gid - NPACK;
    float4 va = *(const float4*)(x + (size_t)i8 * 8);
    float4 vb = *(const float4*)(x + (size_t)i8 * 8 + 4);
    uint4 p;
    p.x = (u32)f2bf(va.x) | ((u32)f2bf(va.y) << 16);
    p.y = (u32)f2bf(va.z) | ((u32)f2bf(va.w) << 16);
    p.z = (u32)f2bf(vb.x) | ((u32)f2bf(vb.y) << 16);
    p.w = (u32)f2bf(vb.z) | ((u32)f2bf(vb.w) << 16);
    *(uint4*)(xb + (size_t)i8 * 8) = p;
  } else if (gid < cvtHEnd) {
    int j = gid - cvtXEnd;
    int half = (j >= nh8half);
    int jj = half ? j - nh8half : j;
    float4 va = ((const float4*)hs)[(size_t)j * 2];
    float4 vb = ((const float4*)hs)[(size_t)j * 2 + 1];
    float* fdst = half ? h1f : h0f;
    u16*   bdst = half ? hb1 : hb0;
    ((float4*)fdst)[(size_t)jj * 2]     = va;
    ((float4*)fdst)[(size_t)jj * 2 + 1] = vb;
    uint4 p;
    p.x = (u32)f2bf(va.x) | ((u32)f2bf(va.y) << 16);
    p.y = (u32)f2bf(va.z) | ((u32)f2bf(va.w) << 16);
    p.z = (u32)f2bf(vb.x) | ((u32)f2bf(vb.y) << 16);
    p.w = (u32)f2bf(vb.z) | ((u32)f2bf(vb.w) << 16);
    ((uint4*)bdst)[jj] = p;
  } else if (gid < cntEnd) {
    int e = gid - cvtHEnd;
    atomicAdd(&deg[dst[e]], 1);
  }
}

// ---------------- scan: single block, one barrier phase ----------------
__global__ __launch_bounds__(1024) void scan_kernel(const int* __restrict__ deg,
                                                    int* __restrict__ offs,
                                                    float* __restrict__ dinv, int n) {
  __shared__ int lds_deg[10240];
  __shared__ int wsum[16];
  int tid = threadIdx.x;
  for (int i = tid; i < 10240; i += 1024) lds_deg[i] = (i < n) ? deg[i] : 0;
  __syncthreads();
  int base = tid * 10;
  int loc[10];
  int s = 0;
  #pragma unroll
  for (int k = 0; k < 10; ++k) { loc[k] = s; s += lds_deg[base + k]; }
  int lane = tid & 63;
  int incl = s;
  #pragma unroll
  for (int d = 1; d < 64; d <<= 1) {
    int t2 = __shfl_up(incl, d);
    if (lane >= d) incl += t2;
  }
  int wid = tid >> 6;
  if (lane == 63) wsum[wid] = incl;
  __syncthreads();
  int wpre = 0;
  for (int k = 0; k < wid; ++k) wpre += wsum[k];
  int excl = wpre + incl - s;
  #pragma unroll
  for (int k = 0; k < 10; ++k) {
    int idx = base + k;
    if (idx < n) {
      int d0 = lds_deg[idx];
      offs[idx] = excl + loc[k];
      dinv[idx] = (d0 > 0) ? 1.0f / (float)d0 : 0.0f;
    }
  }
  if (tid == 1023) offs[n] = excl + s;
}

__global__ __launch_bounds__(256) void fill_kernel(const int* __restrict__ src,
                                                   const int* __restrict__ dst,
                                                   const int* __restrict__ offs,
                                                   int* __restrict__ cursor,
                                                   int* __restrict__ csr, int E) {
  int e = blockIdx.x * 256 + threadIdx.x;
  if (e >= E) return;
  int d = dst[e];
  int pos = atomicAdd(&cursor[d], 1);
  csr[offs[d] + pos] = src[e] * 64;                // pre-scaled (u32 stride per node)
}

// ---------------- gather-mean core: one wave = one node, 2 edges per vector instr ----------------
// halves walk interleaved edges via per-half base pointer: NO per-edge cndmask/select VALU.
__device__ __forceinline__ void acc4(u32 vx, u32 vy, float& a, float& b, float& c, float& d) {
  a += bf2f((u16)vx); b += bf2f((u16)(vx >> 16));
  c += bf2f((u16)vy); d += bf2f((u16)(vy >> 16));
}

__device__ __forceinline__ void agg_one2(const int* __restrict__ offs,
                                         const int* __restrict__ csr,
                                         const float* __restrict__ dinv,
                                         const u32* __restrict__ S,
                                         u32* __restrict__ O,
                                         int node, int lane) {
  int nu = __builtin_amdgcn_readfirstlane(node);   // wave-uniform -> scalar loads
  int e0 = offs[nu], e1 = offs[nu + 1];
  float di = dinv[nu];
  int half = lane >> 5;                            // lanes 0-31: even edges, 32-63: odd edges
  int col = (lane & 31) * 2;                       // u32 offset in row (uint2 per lane)
  const int* cb = csr + e0 + half;                 // per-half edge walk, stride 2
  int cnt = e1 - e0;
  int pairs = (cnt - half + 1) >> 1;               // half0: ceil(cnt/2), half1: floor(cnt/2)
  float a0 = 0, b0 = 0, c0 = 0, d0 = 0, a1 = 0, b1 = 0, c1 = 0, d1 = 0;
  int i = 0;
  for (; i + 4 <= pairs; i += 4) {                 // 8 edges/wave-iter, 4 gathers in flight
    int q0 = cb[0], q1 = cb[2], q2 = cb[4], q3 = cb[6];
    cb += 8;
    uint2 v0 = *(const uint2*)(S + q0 + col);
    uint2 v1 = *(const uint2*)(S + q1 + col);
    uint2 v2 = *(const uint2*)(S + q2 + col);
    uint2 v3 = *(const uint2*)(S + q3 + col);
    acc4(v0.x, v0.y, a0, b0, c0, d0);
    acc4(v1.x, v1.y, a1, b1, c1, d1);
    acc4(v2.x, v2.y, a0, b0, c0, d0);
    acc4(v3.x, v3.y, a1, b1, c1, d1);
  }
  for (; i < pairs; ++i) {
    int q = cb[0];
    cb += 2;
    uint2 v = *(const uint2*)(S + q + col);
    acc4(v.x, v.y, a0, b0, c0, d0);
  }
  float sa = a0 + a1, sb = b0 + b1, sc = c0 + c1, sd = d0 + d1;
  sa += __shfl_down(sa, 32);
  sb += __shfl_down(sb, 32);
  sc += __shfl_down(sc, 32);
  sd += __shfl_down(sd, 32);
  if (!half) {
    uint2 o;
    o.x = (u32)f2bf(sa * di) | ((u32)f2bf(sb * di) << 16);
    o.y = (u32)f2bf(sc * di) | ((u32)f2bf(sd * di) << 16);
    *(uint2*)(O + (size_t)nu * 64 + col) = o;
  }
}

// x-agg, t-sharded by XCD slot (one 2.56MB t-slice per XCD) + folded initial h0 agg.
// grid = 32500: [0,20000): t=id&7; [20000,30000): t=8+(slot&3); [30000,32500): h0 init.
__global__ __launch_bounds__(256) void aggx_kernel(const int* __restrict__ offs,
                                                   const int* __restrict__ csr,
                                                   const float* __restrict__ dinv,
                                                   const u16* __restrict__ xb,
                                                   u16* __restrict__ axb,
                                                   const u16* __restrict__ hb0,
                                                   u16* __restrict__ ah0, int N) {
  int id = blockIdx.x;
  const u32* S; u32* O; int grp;
  if (id < 20000) {
    int t = id & 7; grp = id >> 3;
    S = (const u32*)xb + (size_t)t * N * 64; O = (u32*)axb + (size_t)t * N * 64;
  } else if (id < 30000) {
    int j = id - 20000;
    int slot = j & 7;
    int t = 8 + (slot & 3);
    grp = (slot >> 2) * 1250 + (j >> 3);
    S = (const u32*)xb + (size_t)t * N * 64; O = (u32*)axb + (size_t)t * N * 64;
  } else {
    grp = id - 30000;
    S = (const u32*)hb0; O = (u32*)ah0;
  }
  int node = grp * 4 + (threadIdx.x >> 6);
  if (node >= N) return;
  agg_one2(offs, csr, dinv, S, O, node, threadIdx.x & 63);
}

// dual agg, XCD-sharded: XCD slots 0-3 -> source0, 4-7 -> source1.
__global__ __launch_bounds__(256) void aggdual_kernel(const int* __restrict__ offs,
                                                      const int* __restrict__ csr,
                                                      const float* __restrict__ dinv,
                                                      const u16* __restrict__ s0,
                                                      const u16* __restrict__ s1,
                                                      u16* __restrict__ o0,
                                                      u16* __restrict__ o1, int N) {
  int b = blockIdx.x;
  int srcsel = (b >> 2) & 1;
  int idx = (b >> 3) * 4 + (b & 3);
  int node = idx * 4 + (threadIdx.x >> 6);
  if (node >= N) return;
  const u32* S = (const u32*)(srcsel ? s1 : s0);
  u32* O = (u32*)(srcsel ? o1 : o0);
  agg_one2(offs, csr, dinv, S, O, node, threadIdx.x & 63);
}

// ---------------- cell/GEMM body ----------------
// tile 64 rows x 256 cols, 512 threads (8 waves), K=512: A=[s0|s1|s2|s3]
// Double-buffered global_load_lds staging (T3-minimum): STAGE(kc+1) issued before
// compute(kc); one counted-drain barrier per iter. LDS: 2 x (8KB A + 32KB B) = 80KB.
// MODE 2: cell + h-update + fused out GEMM; MODE 3: cell + h-update only
template <int MODE>
__device__ __forceinline__ void cell_body(char* __restrict__ smem, int row0, int tid,
    const u16* __restrict__ s0, const u16* __restrict__ s1,
    const u16* __restrict__ s2, const u16* __restrict__ s3,
    const u16* __restrict__ W, const float* __restrict__ bias,
    const float* __restrict__ hin, float* __restrict__ hout, u16* __restrict__ hbout,
    const u16* __restrict__ WoT, const float* __restrict__ bout,
    float* __restrict__ outp, int N) {
  const u16* srcs[4] = {s0, s1, s2, s3};
  int lane = tid & 63, w = tid >> 6;
  int wr = w & 3, wc = w >> 2;

  f32x4 accU[4], accC[4];
  #pragma unroll
  for (int n = 0; n < 4; ++n) { accU[n] = (f32x4){0,0,0,0}; accC[n] = (f32x4){0,0,0,0}; }

  // stage k-chunk kc into buffer bsel
  auto STAGE = [&](int kc, int bsel) {
    char* base = smem + bsel * 40960;
    {
      int r = tid >> 3, k8 = (tid & 7) * 8;
      int k8s = k8 ^ ((r & 7) << 3);
      const u16* g = srcs[kc >> 1] + (size_t)(row0 + r) * DD + (kc & 1) * 64 + k8s;
      gload_lds16(g, (u16*)base + (tid & ~63) * 8);    // rows >= N read in-ws garbage, discarded
    }
    #pragma unroll
    for (int it = 0; it < 4; ++it) {
      int id = it * 512 + tid;
      const u16* g = W + (id >> 3) * 512 + kc * 64 + (id & 7) * 8;
      gload_lds16(g, (u16*)(base + 8192) + (it * 512 + (tid & ~63)) * 8);
    }
  };

  STAGE(0, 0);
  asm volatile("s_waitcnt vmcnt(0)" ::: "memory");
  __builtin_amdgcn_s_barrier();
  asm volatile("" ::: "memory");

  int bsel = 0;
  #pragma unroll
  for (int kc = 0; kc < 8; ++kc) {
    if (kc < 7) STAGE(kc + 1, bsel ^ 1);
    char* As = smem + bsel * 40960;
    char* Bs = As + 8192;
    #pragma unroll
    for (int ks = 0; ks < 2; ++ks) {
      int arow = wr * 16 + (lane & 15);
      int abyte = (arow * 128 + ks * 64 + (lane >> 4) * 16) ^ ((arow & 7) << 4);
      s16x8 af = *(const s16x8*)(As + abyte);
      #pragma unroll
      for (int n = 0; n < 4; ++n) {
        int cu = wc * 64 + n * 16 + (lane & 15);
        int bub = (cu * 128 + ks * 64 + (lane >> 4) * 16) ^ ((cu & 7) << 4);
        s16x8 bu = *(const s16x8*)(Bs + bub);
        accU[n] = __builtin_amdgcn_mfma_f32_16x16x32_bf16(af, bu, accU[n], 0, 0, 0);
        int cc = cu + 128;
        int bcb = (cc * 128 + ks * 64 + (lane >> 4) * 16) ^ ((cc & 7) << 4);
        s16x8 bc = *(const s16x8*)(Bs + bcb);
        accC[n] = __builtin_amdgcn_mfma_f32_16x16x32_bf16(af, bc, accC[n], 0, 0, 0);
      }
    }
    // next-stage loads had compute(kc) to land; drain + barrier (also protects buffer reuse)
    asm volatile("s_waitcnt vmcnt(0)" ::: "memory");
    __builtin_amdgcn_s_barrier();
    asm volatile("" ::: "memory");
    bsel ^= 1;
  }

  // ---- epilogue: u=sigmoid, c=tanh, h' = u*h + (1-u)*c ----
  #pragma unroll
  for (int n = 0; n < 4; ++n) {
    int col = wc * 64 + n * 16 + (lane & 15);
    float bu = bias[col], bc = bias[128 + col];
    #pragma unroll
    for (int r = 0; r < 4; ++r) {
      int row = row0 + wr * 16 + (lane >> 4) * 4 + r;
      if (row < N) {
        float u = 1.0f / (1.0f + __expf(-(accU[n][r] + bu)));
        float cg = tanhf(accC[n][r] + bc);
        size_t idx = (size_t)row * DD + col;
        float hn = u * hin[idx] + (1.0f - u) * cg;
        hout[idx] = hn;
        u16 hnb = f2bf(hn);
        hbout[idx] = hnb;
        if constexpr (MODE == 2) {
          int rl = row - row0;
          int hbyte = (rl * 256 + col * 2) ^ ((rl & 7) << 4);
          *(u16*)(smem + hbyte) = hnb;       // h1' tile overlays buf0 (dead now)
        }
      }
    }
  }
  if constexpr (MODE == 2) {
    #pragma unroll
    for (int it = 0; it < 2; ++it) {
      int id = it * 512 + tid;
      int c = id >> 4, kc8 = (id & 15) * 8;
      uint4 v = *(const uint4*)(WoT + c * 128 + kc8);
      int byte = (c * 256 + kc8 * 2) ^ ((c & 7) << 4);
      *(uint4*)(smem + 16384 + byte) = v;
    }
    __syncthreads();
    f32x4 ao[2] = {};
    #pragma unroll
    for (int ks = 0; ks < 4; ++ks) {
      int arow = wr * 16 + (lane & 15);
      int abyte = (arow * 256 + ks * 64 + (lane >> 4) * 16) ^ ((arow & 7) << 4);
      s16x8 af = *(const s16x8*)(smem + abyte);
      #pragma unroll
      for (int n = 0; n < 2; ++n) {
        int co = wc * 32 + n * 16 + (lane & 15);
        int bbyte = (co * 256 + ks * 64 + (lane >> 4) * 16) ^ ((co & 7) << 4);
        s16x8 bf = *(const s16x8*)(smem + 16384 + bbyte);
        ao[n] = __builtin_amdgcn_mfma_f32_16x16x32_bf16(af, bf, ao[n], 0, 0, 0);
      }
    }
    #pragma unroll
    for (int n = 0; n < 2; ++n) {
      int co = wc * 32 + n * 16 + (lane & 15);
      float bb = bout[co];
      #pragma unroll
      for (int r = 0; r < 4; ++r) {
        int row = row0 + wr * 16 + (lane >> 4) * 4 + r;
        if (row < N) outp[(size_t)row * OO + co] = ao[n][r] + bb;
      }
    }
  }
}

// standalone cell0: h0' = cell(x_t, ax_t, h0, ah0), K=512
__global__ __launch_bounds__(512) void cell0_kernel(const u16* __restrict__ xbt,
                                                    const u16* __restrict__ axbt,
                                                    const u16* __restrict__ hb0c,
                                                    const u16* __restrict__ ah0,
                                                    const u16* __restrict__ W,
                                                    const float* __restrict__ bias,
                                                    const float* __restrict__ h0in,
                                                    float* __restrict__ h0out,
                                                    u16* __restrict__ hb0out, int N) {
  __shared__ __align__(16) char smem[81920];
  cell_body<3>(smem, blockIdx.x * 64, threadIdx.x, xbt, axbt, hb0c, ah0,
               W, bias, h0in, h0out, hb0out, nullptr, nullptr, nullptr, N);
}

// merged step: even blocks = cell1(t)+out(t), odd blocks = cell0(t+1)
template <int WITHC0>
__global__ __launch_bounds__(512) void step_kernel(const u16* __restrict__ xbn,
                                                   const u16* __restrict__ axbn,
                                                   const u16* __restrict__ hb0c,
                                                   const u16* __restrict__ ah0,
                                                   const u16* __restrict__ hb1r,
                                                   const u16* __restrict__ ah1,
                                                   const u16* __restrict__ Wp,
                                                   const float* __restrict__ biasbuf,
                                                   const float* __restrict__ h1in,
                                                   float* __restrict__ h1out,
                                                   u16* __restrict__ hb1w,
                                                   const float* __restrict__ h0in,
                                                   float* __restrict__ h0out,
                                                   u16* __restrict__ hb0out,
                                                   const u16* __restrict__ WoT,
                                                   const float* __restrict__ bout,
                                                   float* __restrict__ outp, int N) {
  __shared__ __align__(16) char smem[81920];
  int bx = blockIdx.x;
  int role = WITHC0 ? (bx & 1) : 0;
  int row0 = (WITHC0 ? (bx >> 1) : bx) * 64;
  if (role == 0) {
    cell_body<2>(smem, row0, threadIdx.x, hb0c, ah0, hb1r, ah1,
                 Wp + 131072, biasbuf + 256,
                 h1in, h1out, hb1w, WoT, bout, outp, N);
  } else {
    cell_body<3>(smem, row0, threadIdx.x, xbn, axbn, hb0c, ah0,
                 Wp, biasbuf,
                 h0in, h0out, hb0out, nullptr, nullptr, nullptr, N);
  }
}

extern "C" void kernel_launch(void* const* d_in, const int* in_sizes, int n_in,
                              void* d_out, int out_size, void* d_ws, size_t ws_size,
                              hipStream_t stream) {
  const float* x      = (const float*)d_in[0];  // [T,N,D]
  const float* hs     = (const float*)d_in[1];  // [L,N,D]
  const float* Wself  = (const float*)d_in[2];  // [L,6,D,D]
  const float* Wneigh = (const float*)d_in[3];
  const float* b      = (const float*)d_in[4];  // [L,6,D]
  const float* Wout   = (const float*)d_in[5];  // [D,OUT]
  const float* bout   = (const float*)d_in[6];  // [OUT]
  const int*   src    = (const int*)d_in[7];    // [E]
  const int*   dst    = (const int*)d_in[8];    // [E]
  float* out = (float*)d_out;

  const int N = NN, E = EE, D = DD, T = TT;

  char* ws = (char*)d_ws;
  size_t off = 0;
  auto alloc = [&](size_t bytes) -> void* {
    void* p = ws + off;
    off = (off + bytes + 255) & ~(size_t)255;
    return p;
  };
  int*   deg     = (int*)alloc(N * 4);
  int*   offs    = (int*)alloc((N + 1) * 4);
  int*   cursor  = (int*)alloc(N * 4);
  int*   csr     = (int*)alloc(E * 4);
  float* dinv    = (float*)alloc(N * 4);
  u16*   Wp      = (u16*)alloc(2 * 256 * 512 * 2);
  float* biasbuf = (float*)alloc(512 * 4);
  u16*   WoT     = (u16*)alloc(64 * 128 * 2);
  float* h0A     = (float*)alloc((size_t)N * D * 4);
  float* h0B     = (float*)alloc((size_t)N * D * 4);
  float* h1f     = (float*)alloc((size_t)N * D * 4);
  u16*   hb0A    = (u16*)alloc((size_t)N * D * 2);
  u16*   hb0B    = (u16*)alloc((size_t)N * D * 2);
  u16*   hb1     = (u16*)alloc((size_t)N * D * 2);
  u16*   ah0b    = (u16*)alloc((size_t)N * D * 2);
  u16*   ah1b    = (u16*)alloc((size_t)N * D * 2);
  u16*   xb      = (u16*)alloc((size_t)T * N * D * 2);
  u16*   axb     = (u16*)alloc((size_t)T * N * D * 2);
  (void)alloc(65536);   // overrun pad for OOB-row staging reads

  float* h0f[2] = {h0A, h0B};
  u16*   hb0[2] = {hb0A, hb0B};
  float* hid0 = out + (size_t)T * N * OO;              // final hidden[0]
  float* hid1 = hid0 + (size_t)N * D;                  // final hidden[1]

  hipMemsetAsync(deg, 0, N * 4, stream);
  hipMemsetAsync(cursor, 0, N * 4, stream);
  {
    int nx8 = T * N * D / 8, nh8half = N * D / 8;
    int NPACK = 2 * 256 * 512 + 64 * 128 + 512;
    int tot = NPACK + nx8 + 2 * nh8half + E;
    prep_kernel<<<(tot + 255) / 256, 256, 0, stream>>>(
        x, hs, dst, Wself, Wneigh, b, Wout,
        xb, h0A, hb0A, h1f, hb1, deg, Wp, biasbuf, WoT, nx8, nh8half, E);
  }
  scan_kernel<<<1, 1024, 0, stream>>>(deg, offs, dinv, N);
  fill_kernel<<<(E + 255) / 256, 256, 0, stream>>>(src, dst, offs, cursor, csr, E);

  int aggGrid = (N + 3) / 4;   // 2500
  int mmGrid  = (N + 63) / 64; // 157

  // t-sharded agg(x_t) for all t + folded agg(h0_init)
  aggx_kernel<<<32500, 256, 0, stream>>>(offs, csr, dinv, xb, axb, hb0A, ah0b, N);
  // cell0(0): K=512 [x_0 | ax_0 | h0 | ah0]; reads h0A, writes h0B
  cell0_kernel<<<mmGrid, 512, 0, stream>>>(xb, axb, hb0A, ah0b, Wp, biasbuf,
                                           h0A, h0B, hb0B, N);

  for (int t = 0; t < T; ++t) {
    u16* cur = hb0[(t + 1) & 1];   // h0'(t) bf16
    // XCD-sharded dual agg: agg(h0'(t)) and agg(h1'(t-1) or h1_init)
    aggdual_kernel<<<2 * aggGrid, 256, 0, stream>>>(offs, csr, dinv, cur, hb1,
                                                    ah0b, ah1b, N);
    if (t < T - 1) {
      // cell1(t)+out merged with cell0(t+1) (K=512, ping-pong h0).
      float* h0o = (t == T - 2) ? hid0 : h0f[t & 1];
      step_kernel<1><<<2 * mmGrid, 512, 0, stream>>>(
          xb + (size_t)(t + 1) * N * D, axb + (size_t)(t + 1) * N * D,
          cur, ah0b, hb1, ah1b, Wp, biasbuf,
          h1f, h1f, hb1,
          h0f[(t + 1) & 1], h0o, hb0[t & 1],
          WoT, bout, out + (size_t)t * N * OO, N);
    } else {
      // t==11: final cell1 -> write final h1 fp32 straight to out
      step_kernel<0><<<mmGrid, 512, 0, stream>>>(
          nullptr, nullptr,
          cur, ah0b, hb1, ah1b, Wp, biasbuf,
          h1f, hid1, hb1, nullptr, nullptr, nullptr,
          WoT, bout, out + (size_t)t * N * OO, N);
    }
  }
}

// Round 10
// 602.695 us; speedup vs baseline: 1.0698x; 1.0698x over previous
//
#include <hip/hip_runtime.h>

typedef unsigned short u16;
typedef unsigned int   u32;
typedef __attribute__((ext_vector_type(4))) float f32x4;
typedef __attribute__((ext_vector_type(8))) short s16x8;

#define TT 12
#define NN 10000
#define EE 160000
#define DD 128
#define OO 64

__device__ __forceinline__ u16 f2bf(float f) {
  union { float f; u32 u; } x; x.f = f;
  u32 r = x.u + 0x7FFFu + ((x.u >> 16) & 1u);   // RNE
  return (u16)(r >> 16);
}
__device__ __forceinline__ float bf2f(u16 v) {
  union { u32 u; float f; } x; x.u = (u32)v << 16; return x.f;
}

// async global->LDS, 16B per lane; LDS dest = wave-uniform base + lane*16
__device__ __forceinline__ void gload_lds16(const u16* g, u16* l) {
  __builtin_amdgcn_global_load_lds(
      (const __attribute__((address_space(1))) u32*)(const void*)g,
      (__attribute__((address_space(3))) u32*)(void*)l, 16, 0, 0);
}

// ---------------- fused prep: pack (coalesced reads, pre-swizzled Wp) + cvt + count ----------------
__global__ __launch_bounds__(256) void prep_kernel(
    const float* __restrict__ x, const float* __restrict__ hs,
    const int* __restrict__ dst,
    const float* __restrict__ Wself, const float* __restrict__ Wneigh,
    const float* __restrict__ b, const float* __restrict__ Wout,
    u16* __restrict__ xb, float* __restrict__ h0f, u16* __restrict__ hb0,
    float* __restrict__ h1f, u16* __restrict__ hb1,
    int* __restrict__ deg, u16* __restrict__ Wp,
    float* __restrict__ biasbuf, u16* __restrict__ WoT,
    int nx8, int nh8half, int E) {
  int gid = blockIdx.x * 256 + threadIdx.x;
  const int NWP = 2 * 256 * 512;
  const int NPACK = NWP + 64 * 128 + 512;
  int cvtXEnd = NPACK + nx8;
  int cvtHEnd = cvtXEnd + 2 * nh8half;
  int cntEnd  = cvtHEnd + E;
  if (gid < NPACK) {
    int pg = gid;
    if (pg < NWP) {
      // source-linear walk: s = ((j*8+gm)*128 + kd)*128 + cc  -> coalesced reads
      int cc = pg & 127;
      int kd = (pg >> 7) & 127;
      int gm = (pg >> 14) & 7;          // 0-3: Wself g2..5, 4-7: Wneigh g2..5
      int j  = pg >> 17;
      int gate = 2 + (gm & 3);
      int neigh = gm >> 2;
      const float* M = neigh ? Wneigh : Wself;
      float v = M[(((j * 6) + gate) * 128 + kd) * 128 + cc];
      int c = cc + ((gate >= 4) ? 128 : 0);
      int seg = (gate & 1) * 2 + neigh;
      int k = seg * 128 + kd;
      int kc = k >> 6, k6 = k & 63;
      int ksw = ((k6 & ~7) ^ ((c & 7) << 3)) | (k6 & 7);   // pre-swizzle for linear LDS stage
      Wp[(size_t)j * 131072 + c * 512 + kc * 64 + ksw] = f2bf(v);
    } else if (pg < NWP + 64 * 128) {
      int i = pg - NWP;
      int c = i >> 7, k = i & 127;               // WoT[c][k] = Wout[k][c]
      WoT[i] = f2bf(Wout[k * OO + c]);
    } else {
      int i = pg - NWP - 64 * 128;
      int j = i >> 8, g = (i >> 7) & 1, d = i & 127;
      int g1 = g ? 4 : 2, g2 = g ? 5 : 3;
      biasbuf[i] = b[(j * 6 + g1) * 128 + d] + b[(j * 6 + g2) * 128 + d];
    }
  } else if (gid < cvtXEnd) {
    int i8 = gid - NPACK;
    float4 va = *(const float4*)(x + (size_t)i8 * 8);
    float4 vb = *(const float4*)(x + (size_t)i8 * 8 + 4);
    uint4 p;
    p.x = (u32)f2bf(va.x) | ((u32)f2bf(va.y) << 16);
    p.y = (u32)f2bf(va.z) | ((u32)f2bf(va.w) << 16);
    p.z = (u32)f2bf(vb.x) | ((u32)f2bf(vb.y) << 16);
    p.w = (u32)f2bf(vb.z) | ((u32)f2bf(vb.w) << 16);
    *(uint4*)(xb + (size_t)i8 * 8) = p;
  } else if (gid < cvtHEnd) {
    int j = gid - cvtXEnd;
    int half = (j >= nh8half);
    int jj = half ? j - nh8half : j;
    float4 va = ((const float4*)hs)[(size_t)j * 2];
    float4 vb = ((const float4*)hs)[(size_t)j * 2 + 1];
    float* fdst = half ? h1f : h0f;
    u16*   bdst = half ? hb1 : hb0;
    ((float4*)fdst)[(size_t)jj * 2]     = va;
    ((float4*)fdst)[(size_t)jj * 2 + 1] = vb;
    uint4 p;
    p.x = (u32)f2bf(va.x) | ((u32)f2bf(va.y) << 16);
    p.y = (u32)f2bf(va.z) | ((u32)f2bf(va.w) << 16);
    p.z = (u32)f2bf(vb.x) | ((u32)f2bf(vb.y) << 16);
    p.w = (u32)f2bf(vb.z) | ((u32)f2bf(vb.w) << 16);
    ((uint4*)bdst)[jj] = p;
  } else if (gid < cntEnd) {
    int e = gid - cvtHEnd;
    atomicAdd(&deg[dst[e]], 1);
  }
}

// ---------------- scan: single block, one barrier phase ----------------
__global__ __launch_bounds__(1024) void scan_kernel(const int* __restrict__ deg,
                                                    int* __restrict__ offs,
                                                    float* __restrict__ dinv, int n) {
  __shared__ int lds_deg[10240];
  __shared__ int wsum[16];
  int tid = threadIdx.x;
  for (int i = tid; i < 10240; i += 1024) lds_deg[i] = (i < n) ? deg[i] : 0;
  __syncthreads();
  int base = tid * 10;
  int loc[10];
  int s = 0;
  #pragma unroll
  for (int k = 0; k < 10; ++k) { loc[k] = s; s += lds_deg[base + k]; }
  int lane = tid & 63;
  int incl = s;
  #pragma unroll
  for (int d = 1; d < 64; d <<= 1) {
    int t2 = __shfl_up(incl, d);
    if (lane >= d) incl += t2;
  }
  int wid = tid >> 6;
  if (lane == 63) wsum[wid] = incl;
  __syncthreads();
  int wpre = 0;
  for (int k = 0; k < wid; ++k) wpre += wsum[k];
  int excl = wpre + incl - s;
  #pragma unroll
  for (int k = 0; k < 10; ++k) {
    int idx = base + k;
    if (idx < n) {
      int d0 = lds_deg[idx];
      offs[idx] = excl + loc[k];
      dinv[idx] = (d0 > 0) ? 1.0f / (float)d0 : 0.0f;
    }
  }
  if (tid == 1023) offs[n] = excl + s;
}

__global__ __launch_bounds__(256) void fill_kernel(const int* __restrict__ src,
                                                   const int* __restrict__ dst,
                                                   const int* __restrict__ offs,
                                                   int* __restrict__ cursor,
                                                   int* __restrict__ csr, int E) {
  int e = blockIdx.x * 256 + threadIdx.x;
  if (e >= E) return;
  int d = dst[e];
  int pos = atomicAdd(&cursor[d], 1);
  csr[offs[d] + pos] = src[e] * 64;                // pre-scaled (u32 stride per node)
}

// ---------------- gather-mean core (round-7 proven): uniform scalar csr loads +
// value cndmask; 8 edges/iter, 4 uint2 gathers in flight ----------------
__device__ __forceinline__ void acc4(u32 vx, u32 vy, float& a, float& b, float& c, float& d) {
  a += bf2f((u16)vx); b += bf2f((u16)(vx >> 16));
  c += bf2f((u16)vy); d += bf2f((u16)(vy >> 16));
}

__device__ __forceinline__ void agg_one2(const int* __restrict__ offs,
                                         const int* __restrict__ csr,
                                         const float* __restrict__ dinv,
                                         const u32* __restrict__ S,
                                         u32* __restrict__ O,
                                         int node, int lane) {
  int nu = __builtin_amdgcn_readfirstlane(node);   // wave-uniform -> scalar loads
  int e0 = offs[nu], e1 = offs[nu + 1];
  float di = dinv[nu];
  int half = lane >> 5;                            // lanes 0-31: even edge, 32-63: odd edge
  int col = (lane & 31) * 2;                       // u32 offset in row (uint2 per lane)
  float a0 = 0, b0 = 0, c0 = 0, d0 = 0, a1 = 0, b1 = 0, c1 = 0, d1 = 0;
  int e = e0;
  for (; e + 8 <= e1; e += 8) {                    // 8 edges / iter, 4 gathers in flight
    int p0 = csr[e],     p1 = csr[e + 1], p2 = csr[e + 2], p3 = csr[e + 3];
    int p4 = csr[e + 4], p5 = csr[e + 5], p6 = csr[e + 6], p7 = csr[e + 7];
    uint2 v0 = *(const uint2*)(S + (half ? p1 : p0) + col);
    uint2 v1 = *(const uint2*)(S + (half ? p3 : p2) + col);
    uint2 v2 = *(const uint2*)(S + (half ? p5 : p4) + col);
    uint2 v3 = *(const uint2*)(S + (half ? p7 : p6) + col);
    acc4(v0.x, v0.y, a0, b0, c0, d0);
    acc4(v1.x, v1.y, a1, b1, c1, d1);
    acc4(v2.x, v2.y, a0, b0, c0, d0);
    acc4(v3.x, v3.y, a1, b1, c1, d1);
  }
  if (e + 4 <= e1) {
    int p0 = csr[e], p1 = csr[e + 1], p2 = csr[e + 2], p3 = csr[e + 3];
    uint2 v0 = *(const uint2*)(S + (half ? p1 : p0) + col);
    uint2 v1 = *(const uint2*)(S + (half ? p3 : p2) + col);
    acc4(v0.x, v0.y, a0, b0, c0, d0);
    acc4(v1.x, v1.y, a1, b1, c1, d1);
    e += 4;
  }
  if (e + 2 <= e1) {
    int p0 = csr[e], p1 = csr[e + 1];
    uint2 v0 = *(const uint2*)(S + (half ? p1 : p0) + col);
    acc4(v0.x, v0.y, a0, b0, c0, d0);
    e += 2;
  }
  if (e < e1) {                                    // odd tail: half 0 only
    uint2 v0 = *(const uint2*)(S + csr[e] + col);
    if (!half) acc4(v0.x, v0.y, a1, b1, c1, d1);
  }
  float sa = a0 + a1, sb = b0 + b1, sc = c0 + c1, sd = d0 + d1;
  sa += __shfl_down(sa, 32);
  sb += __shfl_down(sb, 32);
  sc += __shfl_down(sc, 32);
  sd += __shfl_down(sd, 32);
  if (!half) {
    uint2 o;
    o.x = (u32)f2bf(sa * di) | ((u32)f2bf(sb * di) << 16);
    o.y = (u32)f2bf(sc * di) | ((u32)f2bf(sd * di) << 16);
    *(uint2*)(O + (size_t)nu * 64 + col) = o;
  }
}

// x-agg, t-sharded by XCD slot (one 2.56MB t-slice per XCD) + folded initial h0 agg.
// grid = 32500: [0,20000): t=id&7; [20000,30000): t=8+(slot&3); [30000,32500): h0 init.
__global__ __launch_bounds__(256) void aggx_kernel(const int* __restrict__ offs,
                                                   const int* __restrict__ csr,
                                                   const float* __restrict__ dinv,
                                                   const u16* __restrict__ xb,
                                                   u16* __restrict__ axb,
                                                   const u16* __restrict__ hb0,
                                                   u16* __restrict__ ah0, int N) {
  int id = blockIdx.x;
  const u32* S; u32* O; int grp;
  if (id < 20000) {
    int t = id & 7; grp = id >> 3;
    S = (const u32*)xb + (size_t)t * N * 64; O = (u32*)axb + (size_t)t * N * 64;
  } else if (id < 30000) {
    int j = id - 20000;
    int slot = j & 7;
    int t = 8 + (slot & 3);
    grp = (slot >> 2) * 1250 + (j >> 3);
    S = (const u32*)xb + (size_t)t * N * 64; O = (u32*)axb + (size_t)t * N * 64;
  } else {
    grp = id - 30000;
    S = (const u32*)hb0; O = (u32*)ah0;
  }
  int node = grp * 4 + (threadIdx.x >> 6);
  if (node >= N) return;
  agg_one2(offs, csr, dinv, S, O, node, threadIdx.x & 63);
}

// dual agg, XCD-sharded: XCD slots 0-3 -> source0, 4-7 -> source1.
__global__ __launch_bounds__(256) void aggdual_kernel(const int* __restrict__ offs,
                                                      const int* __restrict__ csr,
                                                      const float* __restrict__ dinv,
                                                      const u16* __restrict__ s0,
                                                      const u16* __restrict__ s1,
                                                      u16* __restrict__ o0,
                                                      u16* __restrict__ o1, int N) {
  int b = blockIdx.x;
  int srcsel = (b >> 2) & 1;
  int idx = (b >> 3) * 4 + (b & 3);
  int node = idx * 4 + (threadIdx.x >> 6);
  if (node >= N) return;
  const u32* S = (const u32*)(srcsel ? s1 : s0);
  u32* O = (u32*)(srcsel ? o1 : o0);
  agg_one2(offs, csr, dinv, S, O, node, threadIdx.x & 63);
}

// ---------------- cell/GEMM body ----------------
// tile 64 rows x 256 cols, 512 threads (8 waves), K=512: A=[s0|s1|s2|s3]
// Double-buffered global_load_lds staging: STAGE(kc+1) issued before compute(kc);
// one drain barrier per iter. LDS: 2 x (8KB A + 32KB B) = 80KB.
// MODE 2: cell + h-update + fused out GEMM; MODE 3: cell + h-update only
template <int MODE>
__device__ __forceinline__ void cell_body(char* __restrict__ smem, int row0, int tid,
    const u16* __restrict__ s0, const u16* __restrict__ s1,
    const u16* __restrict__ s2, const u16* __restrict__ s3,
    const u16* __restrict__ W, const float* __restrict__ bias,
    const float* __restrict__ hin, float* __restrict__ hout, u16* __restrict__ hbout,
    const u16* __restrict__ WoT, const float* __restrict__ bout,
    float* __restrict__ outp, int N) {
  const u16* srcs[4] = {s0, s1, s2, s3};
  int lane = tid & 63, w = tid >> 6;
  int wr = w & 3, wc = w >> 2;

  f32x4 accU[4], accC[4];
  #pragma unroll
  for (int n = 0; n < 4; ++n) { accU[n] = (f32x4){0,0,0,0}; accC[n] = (f32x4){0,0,0,0}; }

  // stage k-chunk kc into buffer bsel
  auto STAGE = [&](int kc, int bsel) {
    char* base = smem + bsel * 40960;
    {
      int r = tid >> 3, k8 = (tid & 7) * 8;
      int k8s = k8 ^ ((r & 7) << 3);
      const u16* g = srcs[kc >> 1] + (size_t)(row0 + r) * DD + (kc & 1) * 64 + k8s;
      gload_lds16(g, (u16*)base + (tid & ~63) * 8);    // rows >= N read in-ws garbage, discarded
    }
    #pragma unroll
    for (int it = 0; it < 4; ++it) {
      int id = it * 512 + tid;
      const u16* g = W + (id >> 3) * 512 + kc * 64 + (id & 7) * 8;
      gload_lds16(g, (u16*)(base + 8192) + (it * 512 + (tid & ~63)) * 8);
    }
  };

  STAGE(0, 0);
  asm volatile("s_waitcnt vmcnt(0)" ::: "memory");
  __builtin_amdgcn_s_barrier();
  asm volatile("" ::: "memory");

  int bsel = 0;
  #pragma unroll
  for (int kc = 0; kc < 8; ++kc) {
    if (kc < 7) STAGE(kc + 1, bsel ^ 1);
    char* As = smem + bsel * 40960;
    char* Bs = As + 8192;
    #pragma unroll
    for (int ks = 0; ks < 2; ++ks) {
      int arow = wr * 16 + (lane & 15);
      int abyte = (arow * 128 + ks * 64 + (lane >> 4) * 16) ^ ((arow & 7) << 4);
      s16x8 af = *(const s16x8*)(As + abyte);
      #pragma unroll
      for (int n = 0; n < 4; ++n) {
        int cu = wc * 64 + n * 16 + (lane & 15);
        int bub = (cu * 128 + ks * 64 + (lane >> 4) * 16) ^ ((cu & 7) << 4);
        s16x8 bu = *(const s16x8*)(Bs + bub);
        accU[n] = __builtin_amdgcn_mfma_f32_16x16x32_bf16(af, bu, accU[n], 0, 0, 0);
        int cc = cu + 128;
        int bcb = (cc * 128 + ks * 64 + (lane >> 4) * 16) ^ ((cc & 7) << 4);
        s16x8 bc = *(const s16x8*)(Bs + bcb);
        accC[n] = __builtin_amdgcn_mfma_f32_16x16x32_bf16(af, bc, accC[n], 0, 0, 0);
      }
    }
    // next-stage loads had compute(kc) to land; drain + barrier (also protects buffer reuse)
    asm volatile("s_waitcnt vmcnt(0)" ::: "memory");
    __builtin_amdgcn_s_barrier();
    asm volatile("" ::: "memory");
    bsel ^= 1;
  }

  // ---- epilogue: u=sigmoid, c=tanh, h' = u*h + (1-u)*c ----
  #pragma unroll
  for (int n = 0; n < 4; ++n) {
    int col = wc * 64 + n * 16 + (lane & 15);
    float bu = bias[col], bc = bias[128 + col];
    #pragma unroll
    for (int r = 0; r < 4; ++r) {
      int row = row0 + wr * 16 + (lane >> 4) * 4 + r;
      if (row < N) {
        float u = 1.0f / (1.0f + __expf(-(accU[n][r] + bu)));
        float cg = tanhf(accC[n][r] + bc);
        size_t idx = (size_t)row * DD + col;
        float hn = u * hin[idx] + (1.0f - u) * cg;
        hout[idx] = hn;
        u16 hnb = f2bf(hn);
        hbout[idx] = hnb;
        if constexpr (MODE == 2) {
          int rl = row - row0;
          int hbyte = (rl * 256 + col * 2) ^ ((rl & 7) << 4);
          *(u16*)(smem + hbyte) = hnb;       // h1' tile overlays buf0 (dead now)
        }
      }
    }
  }
  if constexpr (MODE == 2) {
    #pragma unroll
    for (int it = 0; it < 2; ++it) {
      int id = it * 512 + tid;
      int c = id >> 4, kc8 = (id & 15) * 8;
      uint4 v = *(const uint4*)(WoT + c * 128 + kc8);
      int byte = (c * 256 + kc8 * 2) ^ ((c & 7) << 4);
      *(uint4*)(smem + 16384 + byte) = v;
    }
    __syncthreads();
    f32x4 ao[2] = {};
    #pragma unroll
    for (int ks = 0; ks < 4; ++ks) {
      int arow = wr * 16 + (lane & 15);
      int abyte = (arow * 256 + ks * 64 + (lane >> 4) * 16) ^ ((arow & 7) << 4);
      s16x8 af = *(const s16x8*)(smem + abyte);
      #pragma unroll
      for (int n = 0; n < 2; ++n) {
        int co = wc * 32 + n * 16 + (lane & 15);
        int bbyte = (co * 256 + ks * 64 + (lane >> 4) * 16) ^ ((co & 7) << 4);
        s16x8 bf = *(const s16x8*)(smem + 16384 + bbyte);
        ao[n] = __builtin_amdgcn_mfma_f32_16x16x32_bf16(af, bf, ao[n], 0, 0, 0);
      }
    }
    #pragma unroll
    for (int n = 0; n < 2; ++n) {
      int co = wc * 32 + n * 16 + (lane & 15);
      float bb = bout[co];
      #pragma unroll
      for (int r = 0; r < 4; ++r) {
        int row = row0 + wr * 16 + (lane >> 4) * 4 + r;
        if (row < N) outp[(size_t)row * OO + co] = ao[n][r] + bb;
      }
    }
  }
}

// standalone cell0: h0' = cell(x_t, ax_t, h0, ah0), K=512
__global__ __launch_bounds__(512) void cell0_kernel(const u16* __restrict__ xbt,
                                                    const u16* __restrict__ axbt,
                                                    const u16* __restrict__ hb0c,
                                                    const u16* __restrict__ ah0,
                                                    const u16* __restrict__ W,
                                                    const float* __restrict__ bias,
                                                    const float* __restrict__ h0in,
                                                    float* __restrict__ h0out,
                                                    u16* __restrict__ hb0out, int N) {
  __shared__ __align__(16) char smem[81920];
  cell_body<3>(smem, blockIdx.x * 64, threadIdx.x, xbt, axbt, hb0c, ah0,
               W, bias, h0in, h0out, hb0out, nullptr, nullptr, nullptr, N);
}

// merged step: even blocks = cell1(t)+out(t), odd blocks = cell0(t+1)
template <int WITHC0>
__global__ __launch_bounds__(512) void step_kernel(const u16* __restrict__ xbn,
                                                   const u16* __restrict__ axbn,
                                                   const u16* __restrict__ hb0c,
                                                   const u16* __restrict__ ah0,
                                                   const u16* __restrict__ hb1r,
                                                   const u16* __restrict__ ah1,
                                                   const u16* __restrict__ Wp,
                                                   const float* __restrict__ biasbuf,
                                                   const float* __restrict__ h1in,
                                                   float* __restrict__ h1out,
                                                   u16* __restrict__ hb1w,
                                                   const float* __restrict__ h0in,
                                                   float* __restrict__ h0out,
                                                   u16* __restrict__ hb0out,
                                                   const u16* __restrict__ WoT,
                                                   const float* __restrict__ bout,
                                                   float* __restrict__ outp, int N) {
  __shared__ __align__(16) char smem[81920];
  int bx = blockIdx.x;
  int role = WITHC0 ? (bx & 1) : 0;
  int row0 = (WITHC0 ? (bx >> 1) : bx) * 64;
  if (role == 0) {
    cell_body<2>(smem, row0, threadIdx.x, hb0c, ah0, hb1r, ah1,
                 Wp + 131072, biasbuf + 256,
                 h1in, h1out, hb1w, WoT, bout, outp, N);
  } else {
    cell_body<3>(smem, row0, threadIdx.x, xbn, axbn, hb0c, ah0,
                 Wp, biasbuf,
                 h0in, h0out, hb0out, nullptr, nullptr, nullptr, N);
  }
}

extern "C" void kernel_launch(void* const* d_in, const int* in_sizes, int n_in,
                              void* d_out, int out_size, void* d_ws, size_t ws_size,
                              hipStream_t stream) {
  const float* x      = (const float*)d_in[0];  // [T,N,D]
  const float* hs     = (const float*)d_in[1];  // [L,N,D]
  const float* Wself  = (const float*)d_in[2];  // [L,6,D,D]
  const float* Wneigh = (const float*)d_in[3];
  const float* b      = (const float*)d_in[4];  // [L,6,D]
  const float* Wout   = (const float*)d_in[5];  // [D,OUT]
  const float* bout   = (const float*)d_in[6];  // [OUT]
  const int*   src    = (const int*)d_in[7];    // [E]
  const int*   dst    = (const int*)d_in[8];    // [E]
  float* out = (float*)d_out;

  const int N = NN, E = EE, D = DD, T = TT;

  char* ws = (char*)d_ws;
  size_t off = 0;
  auto alloc = [&](size_t bytes) -> void* {
    void* p = ws + off;
    off = (off + bytes + 255) & ~(size_t)255;
    return p;
  };
  int*   deg     = (int*)alloc(N * 4);
  int*   offs    = (int*)alloc((N + 1) * 4);
  int*   cursor  = (int*)alloc(N * 4);
  int*   csr     = (int*)alloc(E * 4);
  float* dinv    = (float*)alloc(N * 4);
  u16*   Wp      = (u16*)alloc(2 * 256 * 512 * 2);
  float* biasbuf = (float*)alloc(512 * 4);
  u16*   WoT     = (u16*)alloc(64 * 128 * 2);
  float* h0A     = (float*)alloc((size_t)N * D * 4);
  float* h0B     = (float*)alloc((size_t)N * D * 4);
  float* h1f     = (float*)alloc((size_t)N * D * 4);
  u16*   hb0A    = (u16*)alloc((size_t)N * D * 2);
  u16*   hb0B    = (u16*)alloc((size_t)N * D * 2);
  u16*   hb1     = (u16*)alloc((size_t)N * D * 2);
  u16*   ah0b    = (u16*)alloc((size_t)N * D * 2);
  u16*   ah1b    = (u16*)alloc((size_t)N * D * 2);
  u16*   xb      = (u16*)alloc((size_t)T * N * D * 2);
  u16*   axb     = (u16*)alloc((size_t)T * N * D * 2);
  (void)alloc(65536);   // overrun pad for OOB-row staging reads

  float* h0f[2] = {h0A, h0B};
  u16*   hb0[2] = {hb0A, hb0B};
  float* hid0 = out + (size_t)T * N * OO;              // final hidden[0]
  float* hid1 = hid0 + (size_t)N * D;                  // final hidden[1]

  hipMemsetAsync(deg, 0, N * 4, stream);
  hipMemsetAsync(cursor, 0, N * 4, stream);
  {
    int nx8 = T * N * D / 8, nh8half = N * D / 8;
    int NPACK = 2 * 256 * 512 + 64 * 128 + 512;
    int tot = NPACK + nx8 + 2 * nh8half + E;
    prep_kernel<<<(tot + 255) / 256, 256, 0, stream>>>(
        x, hs, dst, Wself, Wneigh, b, Wout,
        xb, h0A, hb0A, h1f, hb1, deg, Wp, biasbuf, WoT, nx8, nh8half, E);
  }
  scan_kernel<<<1, 1024, 0, stream>>>(deg, offs, dinv, N);
  fill_kernel<<<(E + 255) / 256, 256, 0, stream>>>(src, dst, offs, cursor, csr, E);

  int aggGrid = (N + 3) / 4;   // 2500
  int mmGrid  = (N + 63) / 64; // 157

  // t-sharded agg(x_t) for all t + folded agg(h0_init)
  aggx_kernel<<<32500, 256, 0, stream>>>(offs, csr, dinv, xb, axb, hb0A, ah0b, N);
  // cell0(0): K=512 [x_0 | ax_0 | h0 | ah0]; reads h0A, writes h0B
  cell0_kernel<<<mmGrid, 512, 0, stream>>>(xb, axb, hb0A, ah0b, Wp, biasbuf,
                                           h0A, h0B, hb0B, N);

  for (int t = 0; t < T; ++t) {
    u16* cur = hb0[(t + 1) & 1];   // h0'(t) bf16
    // XCD-sharded dual agg: agg(h0'(t)) and agg(h1'(t-1) or h1_init)
    aggdual_kernel<<<2 * aggGrid, 256, 0, stream>>>(offs, csr, dinv, cur, hb1,
                                                    ah0b, ah1b, N);
    if (t < T - 1) {
      // cell1(t)+out merged with cell0(t+1) (K=512, ping-pong h0).
      float* h0o = (t == T - 2) ? hid0 : h0f[t & 1];
      step_kernel<1><<<2 * mmGrid, 512, 0, stream>>>(
          xb + (size_t)(t + 1) * N * D, axb + (size_t)(t + 1) * N * D,
          cur, ah0b, hb1, ah1b, Wp, biasbuf,
          h1f, h1f, hb1,
          h0f[(t + 1) & 1], h0o, hb0[t & 1],
          WoT, bout, out + (size_t)t * N * OO, N);
    } else {
      // t==11: final cell1 -> write final h1 fp32 straight to out
      step_kernel<0><<<mmGrid, 512, 0, stream>>>(
          nullptr, nullptr,
          cur, ah0b, hb1, ah1b, Wp, biasbuf,
          h1f, hid1, hb1, nullptr, nullptr, nullptr,
          WoT, bout, out + (size_t)t * N * OO, N);
    }
  }
}